// Round 1
// baseline (290034.546 us; speedup 1.0000x reference)
//
#include <hip/hip_runtime.h>
#include <stdint.h>

#define L4   250   // chase chunk length
#define GRP  50    // chunks per map-composition group
#define PF   8     // feat prefetch depth in k_forward

// ---------------------------------------------------------------------------
// K1: exact sequential Viterbi forward pass. ONE wave (64 threads, 1 block).
// Replicates reference fp32 op order bit-exactly:
//   fv'[n] = fl( fl( max_p fl(fv[p] + trans[n,p]) ) + feat[t,n] )
// argmax tie-break = first (lowest) p, via strict-greater scan.
// Emits backpointers as bytes bp[t*16+n], and final argmax tag.
// ---------------------------------------------------------------------------
__global__ __launch_bounds__(64)
void k_forward(const float* __restrict__ feats, const float* __restrict__ trans,
               unsigned char* __restrict__ bp, int* __restrict__ last_tag, int T) {
  const int lane = threadIdx.x;   // 0..63
  const int n = lane & 15;        // lanes 16..63 mirror lanes 0..15

  float tr[16];
  #pragma unroll
  for (int p = 0; p < 16; ++p) tr[p] = trans[n * 16 + p];

  float fv[16];
  #pragma unroll
  for (int p = 0; p < 16; ++p) fv[p] = 0.0f;

  float fbuf[PF];
  #pragma unroll
  for (int i = 0; i < PF; ++i) fbuf[i] = feats[i * 16 + n];

  for (int tb = 0; tb < T; tb += PF) {
    #pragma unroll
    for (int u = 0; u < PF; ++u) {
      const int t = tb + u;
      // argmax_p (fv[p] + tr[p]), first-index tie-break (strict >)
      float best = fv[0] + tr[0];
      int bi = 0;
      #pragma unroll
      for (int p = 1; p < 16; ++p) {
        float v = fv[p] + tr[p];
        if (v > best) { best = v; bi = p; }
      }
      float nf = best + fbuf[u];
      // prefetch feat for step t+PF (clamped; clamp only matters for last PF steps)
      int pfi = t + PF; if (pfi > T - 1) pfi = T - 1;
      fbuf[u] = feats[(size_t)pfi * 16 + n];
      if (lane < 16) bp[(size_t)t * 16 + n] = (unsigned char)bi;
      // broadcast new fv vector to all lanes
      #pragma unroll
      for (int p = 0; p < 16; ++p) fv[p] = __shfl(nf, p, 64);
    }
  }
  if (lane == 0) {
    float b = fv[0]; int bi = 0;
    #pragma unroll
    for (int p = 1; p < 16; ++p) { if (fv[p] > b) { b = fv[p]; bi = p; } }
    *last_tag = bi;
  }
}

// ---------------------------------------------------------------------------
// K2: per-chunk 16-hypothesis backtrack (exact integer pointer chase).
// Chunk covers t in [a,b). Hypothesis h = tag at time b-1.
// st[t*16+h] = tag at time t-1 given hypothesis h (this IS out[t] if h true).
// maps[c*16+h] = tag at time a-1 given h (chunk's end->start map).
// 4 chunks per wave (16 lanes each).
// ---------------------------------------------------------------------------
__global__ __launch_bounds__(64)
void k_chase(const unsigned char* __restrict__ bp, unsigned char* __restrict__ st,
             unsigned char* __restrict__ maps, int T, int C) {
  const int tid = threadIdx.x;
  const int chunk = blockIdx.x * 4 + (tid >> 4);
  const int h = tid & 15;
  if (chunk >= C) return;
  const int a = chunk * L4;
  int b = a + L4; if (b > T) b = T;
  int cur = h;
  for (int t = b - 1; t >= a; --t) {
    cur = bp[(size_t)t * 16 + cur];
    st[(size_t)t * 16 + h] = (unsigned char)cur;
  }
  maps[chunk * 16 + h] = (unsigned char)cur;
}

// ---------------------------------------------------------------------------
// K3: compose GRP consecutive chunk maps into one super-map per group.
// super[g] = m_{g*GRP} o m_{g*GRP+1} o ... (apply latest chunk first)
// ---------------------------------------------------------------------------
__global__ __launch_bounds__(64)
void k_group(const unsigned char* __restrict__ maps, unsigned char* __restrict__ sup,
             int C, int NG) {
  const int g = blockIdx.x;
  const int e = threadIdx.x;
  if (g >= NG || e >= 16) return;
  int hi = g * GRP + GRP - 1; if (hi > C - 1) hi = C - 1;
  int cur = e;
  for (int c = hi; c >= g * GRP; --c) cur = maps[c * 16 + cur];
  sup[g * 16 + e] = (unsigned char)cur;
}

// ---------------------------------------------------------------------------
// K4: resolve true tag at every chunk's end boundary.
// Phase 1 (thread 0): walk super-maps from the end -> tag at each group's
// end boundary. Phase 2 (thread per group): walk chunk maps within group.
// s_arr[c] = true tag at time (b_c - 1).
// ---------------------------------------------------------------------------
__global__ __launch_bounds__(128)
void k_resolve(const unsigned char* __restrict__ maps, const unsigned char* __restrict__ sup,
               const int* __restrict__ last_tag, unsigned char* __restrict__ s_arr,
               int C, int NG) {
  __shared__ unsigned char Sg[4096];
  const int tid = threadIdx.x;
  if (tid == 0) {
    int cur = *last_tag;
    for (int g = NG - 1; g >= 0; --g) {
      Sg[g] = (unsigned char)cur;
      cur = sup[g * 16 + cur];
    }
  }
  __syncthreads();
  for (int g = tid; g < NG; g += blockDim.x) {
    int cur = Sg[g];
    int hi = g * GRP + GRP - 1; if (hi > C - 1) hi = C - 1;
    for (int c = hi; c >= g * GRP; --c) {
      s_arr[c] = (unsigned char)cur;   // s of chunk c (then step to c-1's)
      cur = maps[c * 16 + cur];
    }
  }
}

// ---------------------------------------------------------------------------
// K5: emit out[t] = st[t*16 + s_arr[t / L4]] as int32.
// ---------------------------------------------------------------------------
__global__ void k_emit(const unsigned char* __restrict__ st,
                       const unsigned char* __restrict__ s_arr,
                       int* __restrict__ out, int T) {
  int t = blockIdx.x * blockDim.x + threadIdx.x;
  if (t < T) out[t] = (int)st[(size_t)t * 16 + s_arr[t / L4]];
}

extern "C" void kernel_launch(void* const* d_in, const int* in_sizes, int n_in,
                              void* d_out, int out_size, void* d_ws, size_t ws_size,
                              hipStream_t stream) {
  const float* feats = (const float*)d_in[0];   // [1, T, 16] fp32
  const float* trans = (const float*)d_in[1];   // [16, 16]  fp32
  int* out = (int*)d_out;                       // [T] int32

  const int T  = in_sizes[0] / 16;
  const int C  = (T + L4 - 1) / L4;
  const int NG = (C + GRP - 1) / GRP;

  char* ws = (char*)d_ws;
  unsigned char* bp   = (unsigned char*)ws;                 // T*16 bytes
  unsigned char* st   = bp + (size_t)T * 16;                // T*16 bytes
  unsigned char* maps = st + (size_t)T * 16;                // C*16
  unsigned char* sup  = maps + (size_t)C * 16;              // NG*16
  unsigned char* sarr = sup + (size_t)NG * 16;              // C
  int* last_tag = (int*)(((uintptr_t)(sarr + C) + 15) & ~(uintptr_t)15);
  size_t need = (size_t)((char*)(last_tag + 1) - ws);
  if (ws_size < need) return;  // insufficient scratch -> fail visibly (absmax ~= 15)

  k_forward<<<1, 64, 0, stream>>>(feats, trans, bp, last_tag, T);
  k_chase<<<(C + 3) / 4, 64, 0, stream>>>(bp, st, maps, T, C);
  k_group<<<NG, 64, 0, stream>>>(maps, sup, C, NG);
  k_resolve<<<1, 128, 0, stream>>>(maps, sup, last_tag, sarr, C, NG);
  const int thr = 256;
  k_emit<<<(T + thr - 1) / thr, thr, 0, stream>>>(st, sarr, out, T);
}

// Round 2
// 87294.434 us; speedup vs baseline: 3.3225x; 3.3225x over previous
//
#include <hip/hip_runtime.h>
#include <stdint.h>

#define L4   250   // chase chunk length
#define GRP  50    // chunks per map-composition group
#define PF   8     // feat prefetch depth in k_chain

// DPP quad_perm helpers (intra-quad cross-lane, VALU-speed, no LDS)
__device__ __forceinline__ float dpp_swap1(float x) { // quad_perm [1,0,3,2]
  return __int_as_float(__builtin_amdgcn_mov_dpp(__float_as_int(x), 0xB1, 0xF, 0xF, false));
}
__device__ __forceinline__ float dpp_swap2(float x) { // quad_perm [2,3,0,1]
  return __int_as_float(__builtin_amdgcn_mov_dpp(__float_as_int(x), 0x4E, 0xF, 0xF, false));
}

// ---------------------------------------------------------------------------
// K1: value-only exact Viterbi forward chain. ONE wave.
// Lane l: n = l>>2 (row / next-tag), j = l&3 (p-group); handles p in {4j..4j+3}.
// Streams FV[t] (fv entering step t) to memory; FV[0] = zeros.
// fp32 max is exact & order-independent -> tree/DPP reduction is bit-exact
// vs the reference's jnp.max. Candidate adds fl(fv[p]+tr[n,p]) identical.
// Backpointers are NOT computed here (k_bp recomputes them in parallel).
// ---------------------------------------------------------------------------
__global__ __launch_bounds__(64)
void k_chain(const float* __restrict__ feats, const float* __restrict__ trans,
             float* __restrict__ FV, int* __restrict__ last_tag, int T) {
  const int l = threadIdx.x;
  const int n = l >> 2;
  const int j = l & 3;

  // trans[n][4j+k]
  const float tr0 = trans[n * 16 + 4 * j + 0];
  const float tr1 = trans[n * 16 + 4 * j + 1];
  const float tr2 = trans[n * 16 + 4 * j + 2];
  const float tr3 = trans[n * 16 + 4 * j + 3];

  // bpermute byte addrs: fv[p] lives in quad p -> lane 4p -> byte addr 16p.
  // p = 4j+k  =>  addr_k = 64j + 16k
  const int a0 = 64 * j + 0;
  const int a1 = 64 * j + 16;
  const int a2 = 64 * j + 32;
  const int a3 = 64 * j + 48;

  float f0 = 0.0f, f1 = 0.0f, f2 = 0.0f, f3 = 0.0f; // fv[4j+k]

  if (l < 16) FV[l] = 0.0f; // FV[0] = init_fv = zeros

  float fbuf[PF];
  #pragma unroll
  for (int i = 0; i < PF; ++i) {
    int idx = i < T ? i : (T - 1);
    fbuf[i] = feats[(size_t)idx * 16 + n];
  }

  int t = 0;
  const int Tm = T - (T % PF);
  for (; t < Tm; t += PF) {
    #pragma unroll
    for (int u = 0; u < PF; ++u) {
      const int tt = t + u;
      // candidates
      float c0 = f0 + tr0, c1 = f1 + tr1, c2 = f2 + tr2, c3 = f3 + tr3;
      // exact max tree (in-lane then intra-quad via DPP)
      float m = fmaxf(fmaxf(c0, c1), fmaxf(c2, c3));
      m = fmaxf(m, dpp_swap1(m));
      m = fmaxf(m, dpp_swap2(m));
      const float nf = m + fbuf[u];
      // prefetch feat for step tt+PF
      int pfi = tt + PF; if (pfi > T - 1) pfi = T - 1;
      fbuf[u] = feats[(size_t)pfi * 16 + n];
      // stream fv entering step tt+1 (one lane per quad)
      if (j == 0) FV[(size_t)(tt + 1) * 16 + n] = nf;
      // redistribute: f_k <- fv[4j+k] from lane 4*(4j+k)
      const int nfi = __float_as_int(nf);
      f0 = __int_as_float(__builtin_amdgcn_ds_bpermute(a0, nfi));
      f1 = __int_as_float(__builtin_amdgcn_ds_bpermute(a1, nfi));
      f2 = __int_as_float(__builtin_amdgcn_ds_bpermute(a2, nfi));
      f3 = __int_as_float(__builtin_amdgcn_ds_bpermute(a3, nfi));
    }
  }
  for (; t < T; ++t) { // tail (T % PF steps)
    float c0 = f0 + tr0, c1 = f1 + tr1, c2 = f2 + tr2, c3 = f3 + tr3;
    float m = fmaxf(fmaxf(c0, c1), fmaxf(c2, c3));
    m = fmaxf(m, dpp_swap1(m));
    m = fmaxf(m, dpp_swap2(m));
    const float nf = m + feats[(size_t)t * 16 + n];
    if (j == 0) FV[(size_t)(t + 1) * 16 + n] = nf;
    const int nfi = __float_as_int(nf);
    f0 = __int_as_float(__builtin_amdgcn_ds_bpermute(a0, nfi));
    f1 = __int_as_float(__builtin_amdgcn_ds_bpermute(a1, nfi));
    f2 = __int_as_float(__builtin_amdgcn_ds_bpermute(a2, nfi));
    f3 = __int_as_float(__builtin_amdgcn_ds_bpermute(a3, nfi));
  }

  // last_tag = argmax of final fv (first-index tie-break).
  // After final redistribute, lane j (j=l&3) holds fv[4j..4j+3] in f0..f3.
  float bv = f0; int bi = 4 * j;
  if (f1 > bv) { bv = f1; bi = 4 * j + 1; }
  if (f2 > bv) { bv = f2; bi = 4 * j + 2; }
  if (f3 > bv) { bv = f3; bi = 4 * j + 3; }
  #pragma unroll
  for (int src = 1; src < 4; ++src) { // lane 0 folds lanes 1..3 (ascending p)
    float ov = __shfl(bv, src, 64);
    int   oi = __shfl(bi, src, 64);
    if (l == 0 && ov > bv) { bv = ov; bi = oi; }
  }
  if (l == 0) *last_tag = bi;
}

// ---------------------------------------------------------------------------
// K2: parallel backpointer recompute. Thread per t.
// bp[t][n] = argmax_p fl(FV[t][p] + tr[n][p]), strict-> scan (first-max),
// bit-identical to the reference's jnp.argmax(scores, axis=1).
// ---------------------------------------------------------------------------
__global__ __launch_bounds__(256)
void k_bp(const float* __restrict__ FV, const float* __restrict__ trans,
          uint4* __restrict__ bp, int T) {
  __shared__ float str[256];
  const int tid = threadIdx.x;
  str[tid] = trans[tid];
  __syncthreads();
  const int t = blockIdx.x * blockDim.x + tid;
  if (t >= T) return;
  const float4* fr = (const float4*)(FV + (size_t)t * 16);
  float4 q0 = fr[0], q1 = fr[1], q2 = fr[2], q3 = fr[3];
  float fv[16] = {q0.x, q0.y, q0.z, q0.w, q1.x, q1.y, q1.z, q1.w,
                  q2.x, q2.y, q2.z, q2.w, q3.x, q3.y, q3.z, q3.w};
  uint32_t w[4];
  #pragma unroll
  for (int g = 0; g < 4; ++g) {
    uint32_t word = 0;
    #pragma unroll
    for (int s = 0; s < 4; ++s) {
      const int nn = 4 * g + s;
      float best = fv[0] + str[nn * 16 + 0];
      int bi = 0;
      #pragma unroll
      for (int p = 1; p < 16; ++p) {
        float v = fv[p] + str[nn * 16 + p];
        if (v > best) { best = v; bi = p; }
      }
      word |= (uint32_t)bi << (8 * s);
    }
    w[g] = word;
  }
  bp[t] = make_uint4(w[0], w[1], w[2], w[3]);
}

// ---------------------------------------------------------------------------
// K3: per-chunk 16-hypothesis backtrack (exact integer pointer chase).
// ---------------------------------------------------------------------------
__global__ __launch_bounds__(64)
void k_chase(const unsigned char* __restrict__ bp, unsigned char* __restrict__ st,
             unsigned char* __restrict__ maps, int T, int C) {
  const int tid = threadIdx.x;
  const int chunk = blockIdx.x * 4 + (tid >> 4);
  const int h = tid & 15;
  if (chunk >= C) return;
  const int a = chunk * L4;
  int b = a + L4; if (b > T) b = T;
  int cur = h;
  for (int t = b - 1; t >= a; --t) {
    cur = bp[(size_t)t * 16 + cur];
    st[(size_t)t * 16 + h] = (unsigned char)cur;
  }
  maps[chunk * 16 + h] = (unsigned char)cur;
}

// ---------------------------------------------------------------------------
// K4: compose GRP consecutive chunk maps into one super-map per group.
// ---------------------------------------------------------------------------
__global__ __launch_bounds__(64)
void k_group(const unsigned char* __restrict__ maps, unsigned char* __restrict__ sup,
             int C, int NG) {
  const int g = blockIdx.x;
  const int e = threadIdx.x;
  if (g >= NG || e >= 16) return;
  int hi = g * GRP + GRP - 1; if (hi > C - 1) hi = C - 1;
  int cur = e;
  for (int c = hi; c >= g * GRP; --c) cur = maps[c * 16 + cur];
  sup[g * 16 + e] = (unsigned char)cur;
}

// ---------------------------------------------------------------------------
// K5: resolve true tag at every chunk's end boundary.
// ---------------------------------------------------------------------------
__global__ __launch_bounds__(128)
void k_resolve(const unsigned char* __restrict__ maps, const unsigned char* __restrict__ sup,
               const int* __restrict__ last_tag, unsigned char* __restrict__ s_arr,
               int C, int NG) {
  __shared__ unsigned char Sg[4096];
  const int tid = threadIdx.x;
  if (tid == 0) {
    int cur = *last_tag;
    for (int g = NG - 1; g >= 0; --g) {
      Sg[g] = (unsigned char)cur;
      cur = sup[g * 16 + cur];
    }
  }
  __syncthreads();
  for (int g = tid; g < NG; g += blockDim.x) {
    int cur = Sg[g];
    int hi = g * GRP + GRP - 1; if (hi > C - 1) hi = C - 1;
    for (int c = hi; c >= g * GRP; --c) {
      s_arr[c] = (unsigned char)cur;
      cur = maps[c * 16 + cur];
    }
  }
}

// ---------------------------------------------------------------------------
// K6: emit out[t] = st[t*16 + s_arr[t / L4]] as int32.
// ---------------------------------------------------------------------------
__global__ void k_emit(const unsigned char* __restrict__ st,
                       const unsigned char* __restrict__ s_arr,
                       int* __restrict__ out, int T) {
  int t = blockIdx.x * blockDim.x + threadIdx.x;
  if (t < T) out[t] = (int)st[(size_t)t * 16 + s_arr[t / L4]];
}

extern "C" void kernel_launch(void* const* d_in, const int* in_sizes, int n_in,
                              void* d_out, int out_size, void* d_ws, size_t ws_size,
                              hipStream_t stream) {
  const float* feats = (const float*)d_in[0];   // [1, T, 16] fp32
  const float* trans = (const float*)d_in[1];   // [16, 16]  fp32
  int* out = (int*)d_out;                       // [T] int32

  const int T  = in_sizes[0] / 16;
  const int C  = (T + L4 - 1) / L4;
  const int NG = (C + GRP - 1) / GRP;

  char* ws = (char*)d_ws;
  float* FV           = (float*)ws;                          // (T+1)*16 floats
  unsigned char* bp   = (unsigned char*)(FV + (size_t)(T + 1) * 16); // T*16 B, 16B-aligned
  unsigned char* st   = bp + (size_t)T * 16;                 // T*16 B
  unsigned char* maps = st + (size_t)T * 16;                 // C*16
  unsigned char* sup  = maps + (size_t)C * 16;               // NG*16
  unsigned char* sarr = sup + (size_t)NG * 16;               // C
  int* last_tag = (int*)(((uintptr_t)(sarr + C) + 15) & ~(uintptr_t)15);
  size_t need = (size_t)((char*)(last_tag + 1) - ws);
  if (ws_size < need) return;  // insufficient scratch -> fail visibly

  k_chain<<<1, 64, 0, stream>>>(feats, trans, FV, last_tag, T);
  k_bp<<<(T + 255) / 256, 256, 0, stream>>>(FV, trans, (uint4*)bp, T);
  k_chase<<<(C + 3) / 4, 64, 0, stream>>>(bp, st, maps, T, C);
  k_group<<<NG, 64, 0, stream>>>(maps, sup, C, NG);
  k_resolve<<<1, 128, 0, stream>>>(maps, sup, last_tag, sarr, C, NG);
  const int thr = 256;
  k_emit<<<(T + thr - 1) / thr, thr, 0, stream>>>(st, sarr, out, T);
}